// Round 5
// baseline (6940.304 us; speedup 1.0000x reference)
//
#include <hip/hip_runtime.h>
#include <hip/hip_bf16.h>
#include <math.h>

typedef __bf16 bf16;
typedef __bf16 bf16x8 __attribute__((ext_vector_type(8)));
typedef float  f32x4  __attribute__((ext_vector_type(4)));

#define MFMA16(a,b,c) __builtin_amdgcn_mfma_f32_16x16x32_bf16(a,b,c,0,0,0)

namespace {

constexpr int Bn = 128, Ln = 64, Tn = 48, En = 512, Hn = 512, Vn = 32000;
constexpr int G4 = 2048;
constexpr int TD = Tn - 1;        // 47 decode steps
constexpr int MD = TD * Bn;       // 6016 rows of final GEMM
constexpr float NEGV = -1e9f;
constexpr int HB = Bn * Hn;       // elems per (B,H) state buffer

__device__ __forceinline__ float sigm(float x){ return 1.f/(1.f+__expf(-x)); }

// async global->LDS 16B per lane; LDS dest = wave-uniform base + lane*16
__device__ __forceinline__ void gload16(const bf16* g, bf16* l){
  __builtin_amdgcn_global_load_lds(
    (const __attribute__((address_space(1))) void*)g,
    (__attribute__((address_space(3))) void*)l, 16, 0, 0);
}

// ---- group barrier: blocks [gbase..gbase+nb) sync via per-block flag slots ----
__device__ __forceinline__ void gbar(int* flags, int gbase, int nb, int slot, int s){
  __builtin_amdgcn_fence(__ATOMIC_RELEASE, "agent");
  __syncthreads();
  if (threadIdx.x == 0)
    __hip_atomic_store(flags + gbase + slot, s, __ATOMIC_RELAXED, __HIP_MEMORY_SCOPE_AGENT);
  if ((int)threadIdx.x < nb){
    int lim = 0;
    while (__hip_atomic_load(flags + gbase + (int)threadIdx.x,
                             __ATOMIC_RELAXED, __HIP_MEMORY_SCOPE_AGENT) < s){
      __builtin_amdgcn_s_sleep(1);
      if (++lim > (1<<18)) break;   // fail-fast instead of deadlock
    }
  }
  __syncthreads();
  __builtin_amdgcn_fence(__ATOMIC_ACQUIRE, "agent");
}

// ---------------- fp32 -> bf16 conversion ----------------
__global__ void k_conv(const float4* __restrict__ s, ushort4* __restrict__ d, int n4){
  int i = blockIdx.x*256 + threadIdx.x;
  if (i >= n4) return;
  float4 v = s[i];
  union { bf16 h[4]; ushort4 u; } pk;
  pk.h[0]=(bf16)v.x; pk.h[1]=(bf16)v.y; pk.h[2]=(bf16)v.z; pk.h[3]=(bf16)v.w;
  d[i] = pk.u;
}

// ---------------- embedding gathers ----------------
__global__ void k_gather_src(const int* __restrict__ toks, const float* __restrict__ emb,
                             ushort4* __restrict__ Xe){
  int i = blockIdx.x*256 + threadIdx.x;      // L*B*E/4 = 1048576
  int e4 = i & (En/4 - 1);
  int r  = i >> 7;
  int l = r >> 7, b = r & (Bn-1);
  int tok = toks[b*Ln + l];
  float4 v = *(const float4*)(emb + (size_t)tok*En + e4*4);
  union { bf16 h[4]; ushort4 u; } pk;
  pk.h[0]=(bf16)v.x; pk.h[1]=(bf16)v.y; pk.h[2]=(bf16)v.z; pk.h[3]=(bf16)v.w;
  Xe[i] = pk.u;
}

__global__ void k_gather_trg(const int* __restrict__ toks, const float* __restrict__ emb,
                             ushort4* __restrict__ Vg){
  int i = blockIdx.x*256 + threadIdx.x;      // TD*B*E/4 = 770048
  int e4 = i & (En/4 - 1);
  int r  = i >> 7;
  int t = r >> 7, b = r & (Bn-1);
  int tok = toks[b*Tn + t];
  float4 v = *(const float4*)(emb + (size_t)tok*En + e4*4);
  union { bf16 h[4]; ushort4 u; } pk;
  pk.h[0]=(bf16)v.x; pk.h[1]=(bf16)v.y; pk.h[2]=(bf16)v.z; pk.h[3]=(bf16)v.w;
  Vg[i] = pk.u;
}

// ---------------- zero-init ----------------
__global__ void k_zero(bf16* __restrict__ h1b0, bf16* __restrict__ h2b1,
                       float* __restrict__ c1, float* __restrict__ c2,
                       int* __restrict__ ef, int* __restrict__ df,
                       float* __restrict__ outp){
  int i = blockIdx.x*256 + threadIdx.x;      // 65536 exact
  h1b0[i] = (bf16)0.f; h2b1[i] = (bf16)0.f; c1[i] = 0.f; c2[i] = 0.f;
  if (i < 256){ ef[i] = 0; df[i] = 0; }
  if (i == 0) outp[0] = 0.f;
}

// ===================== LDS-staged GEMM: C = A(M,512) @ B(N,512)^T + bias =====================
// BM=BN=128, BK=64, 256 thr = 4 waves; wave (wr,wc) computes 64x64.
// XOR-swizzled LDS: slot s of row r holds global k-chunk (s ^ (r&7)).
// MODE 0: bf16 C out. MODE 1: per-row logsumexp partials per 128-col block (pc=blockIdx.y).
template<int MODE>
__global__ void __launch_bounds__(256) k_gemm2(
    const bf16* __restrict__ A, int lda,
    const bf16* __restrict__ Bw, int ldb,
    const float* __restrict__ bias,
    bf16* __restrict__ O, int ldo,
    float* __restrict__ pmax, float* __restrict__ psum, int Mrows)
{
  __shared__ bf16 As[128*64];
  __shared__ bf16 Bs[128*64];
  __shared__ float redm[2][64], reds[2][64];
  int tid = threadIdx.x;
  int lane = tid & 63, w = tid >> 6;
  int wr = w & 1, wc = w >> 1;
  int c15 = lane & 15, hi = lane >> 4;
  int mBase = blockIdx.x*128, nBase = blockIdx.y*128;
  int l8 = lane >> 3;
  int k8 = (lane & 7) ^ l8;                 // swizzled source k-chunk
  int swz = c15 & 7;

  f32x4 acc[4][4] = {};
  int rA[4], cB[4];
  #pragma unroll
  for (int m = 0; m < 4; ++m) rA[m] = (wr*64 + m*16 + c15)*64;
  #pragma unroll
  for (int n = 0; n < 4; ++n) cB[n] = (wc*64 + n*16 + c15)*64;

  for (int kt = 0; kt < 8; ++kt){
    __syncthreads();
    #pragma unroll
    for (int i = 0; i < 4; ++i){
      int s = i*4 + w;
      int row = s*8 + l8;
      gload16(A + (size_t)(mBase+row)*lda + kt*64 + k8*8, As + s*512);
      gload16(Bw + (size_t)(nBase+row)*ldb + kt*64 + k8*8, Bs + s*512);
    }
    __syncthreads();   // drains vmcnt(0): staged data visible
    bf16x8 af[4][2], bf[4][2];
    #pragma unroll
    for (int m = 0; m < 4; ++m)
      #pragma unroll
      for (int j = 0; j < 2; ++j)
        af[m][j] = *(const bf16x8*)(As + rA[m] + (((j*4+hi) ^ swz) << 3));
    #pragma unroll
    for (int n = 0; n < 4; ++n)
      #pragma unroll
      for (int j = 0; j < 2; ++j)
        bf[n][j] = *(const bf16x8*)(Bs + cB[n] + (((j*4+hi) ^ swz) << 3));
    #pragma unroll
    for (int m = 0; m < 4; ++m)
      #pragma unroll
      for (int n = 0; n < 4; ++n){
        acc[m][n] = MFMA16(af[m][0], bf[n][0], acc[m][n]);
        acc[m][n] = MFMA16(af[m][1], bf[n][1], acc[m][n]);
      }
  }

  float bvv[4];
  #pragma unroll
  for (int n = 0; n < 4; ++n) bvv[n] = bias[nBase + wc*64 + n*16 + c15];

  if constexpr (MODE == 0){
    #pragma unroll
    for (int m = 0; m < 4; ++m)
      #pragma unroll
      for (int r = 0; r < 4; ++r){
        size_t ro = (size_t)(mBase + wr*64 + m*16 + hi*4 + r) * ldo + nBase + wc*64;
        #pragma unroll
        for (int n = 0; n < 4; ++n)
          O[ro + n*16 + c15] = (bf16)(acc[m][n][r] + bvv[n]);
      }
  } else {
    float lmx[4][4], lsm[4][4];
    #pragma unroll
    for (int m = 0; m < 4; ++m)
      #pragma unroll
      for (int r = 0; r < 4; ++r){
        float mx = -1e30f;
        #pragma unroll
        for (int n = 0; n < 4; ++n) mx = fmaxf(mx, acc[m][n][r] + bvv[n]);
        mx = fmaxf(mx, __shfl_xor(mx,1)); mx = fmaxf(mx, __shfl_xor(mx,2));
        mx = fmaxf(mx, __shfl_xor(mx,4)); mx = fmaxf(mx, __shfl_xor(mx,8));
        float sm = 0.f;
        #pragma unroll
        for (int n = 0; n < 4; ++n) sm += __expf(acc[m][n][r] + bvv[n] - mx);
        sm += __shfl_xor(sm,1); sm += __shfl_xor(sm,2);
        sm += __shfl_xor(sm,4); sm += __shfl_xor(sm,8);
        lmx[m][r] = mx; lsm[m][r] = sm;
        if (c15 == 0 && wc == 1){
          int rs = m*16 + hi*4 + r;
          redm[wr][rs] = mx; reds[wr][rs] = sm;
        }
      }
    __syncthreads();
    if (wc == 0 && c15 == 0){
      int pc = blockIdx.y;
      #pragma unroll
      for (int m = 0; m < 4; ++m)
        #pragma unroll
        for (int r = 0; r < 4; ++r){
          int rs = m*16 + hi*4 + r;
          float m1 = redm[wr][rs], s1 = reds[wr][rs];
          float M = fmaxf(lmx[m][r], m1);
          float S = lsm[m][r]*__expf(lmx[m][r]-M) + s1*__expf(m1-M);
          size_t o = (size_t)pc*Mrows + mBase + wr*64 + rs;
          pmax[o] = M; psum[o] = S;
        }
    }
  }
}

// ===================== persistent encoder =====================
// 256 blocks x 256 thr. rg=bid>>5 (row group, 16 rows), cb=bid&31 (16 h-cols).
// Per step: layer0(t) + layer1(t-1), K split over 4 waves, LDS reduce, 1 group barrier.
__global__ void __launch_bounds__(256) k_encp(
    const bf16* __restrict__ Xg,
    bf16* __restrict__ h1b, bf16* __restrict__ h2b,
    float* __restrict__ c1, float* __restrict__ c2,
    const bf16* __restrict__ Whh0, const bf16* __restrict__ Wih1,
    const bf16* __restrict__ Whh1, const float* __restrict__ b1,
    const int* __restrict__ slens, bf16* __restrict__ Sst,
    int* __restrict__ flags)
{
  __shared__ float red[2][4][64][17];
  int tid = threadIdx.x;
  int lane = tid & 63, w = tid >> 6;
  int c15 = lane & 15, hi = lane >> 4;
  int rg = blockIdx.x >> 5, cb = blockIdx.x & 31;
  int col = cb*16 + c15;
  int rowA = rg*16 + c15;

  for (int t = 0; t <= Ln; ++t){
    int rb = t & 1;
    // ---- layer0 partials (K quarter w*128) ----
    if (t < Ln){
      f32x4 a0[4] = {};
      const bf16* ap = h1b + rb*HB + (size_t)rowA*Hn + w*128 + hi*8;
      const bf16* bp = Whh0 + (size_t)col*Hn + w*128 + hi*8;
      for (int kb = 0; kb < 4; ++kb){
        bf16x8 av = *(const bf16x8*)(ap + kb*32);
        #pragma unroll
        for (int q = 0; q < 4; ++q){
          bf16x8 bv = *(const bf16x8*)(bp + (size_t)q*(512*512) + kb*32);
          a0[q] = MFMA16(av, bv, a0[q]);
        }
      }
      #pragma unroll
      for (int q = 0; q < 4; ++q)
        #pragma unroll
        for (int r = 0; r < 4; ++r) red[0][w][lane][q*4+r] = a0[q][r];
    }
    // ---- layer1 partials (processes t-1) ----
    if (t >= 1){
      f32x4 a1[4] = {};
      const bf16* ap1 = h1b + rb*HB + (size_t)rowA*Hn + w*128 + hi*8;  // nh1(t-1)
      const bf16* bp1 = Wih1 + (size_t)col*Hn + w*128 + hi*8;
      const bf16* ap2 = h2b + rb*HB + (size_t)rowA*Hn + w*128 + hi*8;
      const bf16* bp2 = Whh1 + (size_t)col*Hn + w*128 + hi*8;
      for (int kb = 0; kb < 4; ++kb){
        bf16x8 av1 = *(const bf16x8*)(ap1 + kb*32);
        bf16x8 av2 = *(const bf16x8*)(ap2 + kb*32);
        #pragma unroll
        for (int q = 0; q < 4; ++q){
          bf16x8 bv1 = *(const bf16x8*)(bp1 + (size_t)q*(512*512) + kb*32);
          bf16x8 bv2 = *(const bf16x8*)(bp2 + (size_t)q*(512*512) + kb*32);
          a1[q] = MFMA16(av1, bv1, a1[q]);
          a1[q] = MFMA16(av2, bv2, a1[q]);
        }
      }
      #pragma unroll
      for (int q = 0; q < 4; ++q)
        #pragma unroll
        for (int r = 0; r < 4; ++r) red[1][w][lane][q*4+r] = a1[q][r];
    }
    __syncthreads();
    // ---- epilogues: each wave handles acc component r = w ----
    int grow = rg*16 + hi*4 + w;
    if (t < Ln){
      float g4[4];
      #pragma unroll
      for (int q = 0; q < 4; ++q)
        g4[q] = red[0][0][lane][q*4+w] + red[0][1][lane][q*4+w]
              + red[0][2][lane][q*4+w] + red[0][3][lane][q*4+w]
              + (float)Xg[((size_t)t*Bn + grow)*G4 + q*Hn + col];
      float cold = c1[grow*Hn + col];
      float iv = sigm(g4[0]), fv = sigm(g4[1]);
      float gv = tanhf(g4[2]), ov = sigm(g4[3]);
      float cn = fv*cold + iv*gv;
      float hn = ov*tanhf(cn);
      bool m = t < slens[grow];
      float hold = (float)h1b[rb*HB + grow*Hn + col];
      c1[grow*Hn + col] = m ? cn : cold;
      h1b[(rb^1)*HB + grow*Hn + col] = (bf16)(m ? hn : hold);
    }
    if (t >= 1){
      int t2 = t - 1;
      float g4[4];
      #pragma unroll
      for (int q = 0; q < 4; ++q)
        g4[q] = red[1][0][lane][q*4+w] + red[1][1][lane][q*4+w]
              + red[1][2][lane][q*4+w] + red[1][3][lane][q*4+w]
              + b1[q*Hn + col];
      float cold = c2[grow*Hn + col];
      float iv = sigm(g4[0]), fv = sigm(g4[1]);
      float gv = tanhf(g4[2]), ov = sigm(g4[3]);
      float cn = fv*cold + iv*gv;
      float hn = ov*tanhf(cn);
      bool m = t2 < slens[grow];
      float hold = (float)h2b[rb*HB + grow*Hn + col];
      c2[grow*Hn + col] = m ? cn : cold;
      h2b[(rb^1)*HB + grow*Hn + col] = (bf16)(m ? hn : hold);
      Sst[((size_t)grow*Ln + t2)*Hn + col] = m ? (bf16)hn : (bf16)0.f;
    }
    gbar(flags, rg*32, 32, cb, t+1);
  }
}

// ===================== persistent decoder =====================
// 256 blocks x 256 thr. Phases: init, then 47 x {gates, attn, hid}, group barriers.
__global__ void __launch_bounds__(256) k_decp(
    const bf16* __restrict__ Gx, const bf16* __restrict__ avall_c,
    bf16* __restrict__ avall, bf16* __restrict__ hdb,
    float* __restrict__ cd, bf16* __restrict__ ctx,
    const bf16* __restrict__ Sst,
    const bf16* __restrict__ Wdih, const bf16* __restrict__ Wdhh,
    const bf16* __restrict__ Whid, const float* __restrict__ hbias,
    const float* __restrict__ iW, const float* __restrict__ ib,
    const float* __restrict__ c1, const float* __restrict__ c2,
    const int* __restrict__ slens, int* __restrict__ flags)
{
  __shared__ float red[4][64][17];
  __shared__ float sc[Ln], at[Ln];
  int tid = threadIdx.x;
  int lane = tid & 63, w = tid >> 6;
  int c15 = lane & 15, hi = lane >> 4;
  int rg = blockIdx.x >> 5, cb = blockIdx.x & 31;
  int col = cb*16 + c15;
  int rowA = rg*16 + c15;

  // ---- init: c0 = [c1|c2] @ iW^T + ib ; h0 = tanh(c0)  (1 out per thread, fp32 VALU) ----
  {
    int r_l = tid >> 4, c_l = tid & 15;
    int row = rg*16 + r_l, ic = cb*16 + c_l;
    const float4* c1v = (const float4*)(c1 + (size_t)row*Hn);
    const float4* c2v = (const float4*)(c2 + (size_t)row*Hn);
    const float4* w1 = (const float4*)(iW + (size_t)ic*1024);
    const float4* w2 = (const float4*)(iW + (size_t)ic*1024 + 512);
    float s = ib[ic];
    for (int k = 0; k < 128; ++k){
      float4 a = c1v[k], b = w1[k];
      s += a.x*b.x + a.y*b.y + a.z*b.z + a.w*b.w;
    }
    for (int k = 0; k < 128; ++k){
      float4 a = c2v[k], b = w2[k];
      s += a.x*b.x + a.y*b.y + a.z*b.z + a.w*b.w;
    }
    cd[(size_t)row*Hn + ic] = s;
    hdb[(size_t)row*Hn + ic] = (bf16)tanhf(s);
  }
  gbar(flags, rg*32, 32, cb, 1);

  for (int t = 0; t < TD; ++t){
    int rb = t & 1;
    int sbase = 2 + t*3;
    // ---------- gates: K=1024 = av(512)|h(512), quarter per wave ----------
    {
      f32x4 acc[4] = {};
      if (w < 2){
        if (t > 0){
          const bf16* ap = avall_c + ((size_t)(t-1)*Bn + rowA)*Hn + w*256 + hi*8;
          const bf16* bp = Wdih + (size_t)col*1024 + 512 + w*256 + hi*8;
          for (int kb = 0; kb < 8; ++kb){
            bf16x8 av = *(const bf16x8*)(ap + kb*32);
            #pragma unroll
            for (int q = 0; q < 4; ++q){
              bf16x8 bv = *(const bf16x8*)(bp + (size_t)q*(512*1024) + kb*32);
              acc[q] = MFMA16(av, bv, acc[q]);
            }
          }
        }
      } else {
        const bf16* ap = hdb + rb*HB + (size_t)rowA*Hn + (w-2)*256 + hi*8;
        const bf16* bp = Wdhh + (size_t)col*Hn + (w-2)*256 + hi*8;
        for (int kb = 0; kb < 8; ++kb){
          bf16x8 av = *(const bf16x8*)(ap + kb*32);
          #pragma unroll
          for (int q = 0; q < 4; ++q){
            bf16x8 bv = *(const bf16x8*)(bp + (size_t)q*(512*512) + kb*32);
            acc[q] = MFMA16(av, bv, acc[q]);
          }
        }
      }
      #pragma unroll
      for (int q = 0; q < 4; ++q)
        #pragma unroll
        for (int r = 0; r < 4; ++r) red[w][lane][q*4+r] = acc[q][r];
      __syncthreads();
      int grow = rg*16 + hi*4 + w;
      float g4[4];
      #pragma unroll
      for (int q = 0; q < 4; ++q)
        g4[q] = red[0][lane][q*4+w] + red[1][lane][q*4+w]
              + red[2][lane][q*4+w] + red[3][lane][q*4+w]
              + (float)Gx[((size_t)t*Bn + grow)*G4 + q*Hn + col];
      float cold = cd[grow*Hn + col];
      float iv = sigm(g4[0]), fv = sigm(g4[1]);
      float gv = tanhf(g4[2]), ov = sigm(g4[3]);
      float cn = fv*cold + iv*gv;
      float hn = ov*tanhf(cn);
      cd[grow*Hn + col] = cn;
      hdb[(rb^1)*HB + grow*Hn + col] = (bf16)hn;
    }
    gbar(flags, rg*32, 32, cb, sbase);
    // ---------- attention: row-local (2 blocks per row, split ctx cols) ----------
    {
      int row = rg*16 + (cb >> 1);
      int half = cb & 1;
      const bf16* h = hdb + (rb^1)*HB + (size_t)row*Hn;
      const bf16* S = Sst + (size_t)row*Ln*Hn;
      int l = tid >> 2, kq = tid & 3;
      float s = 0.f;
      {
        const bf16* hp = h + kq*128;
        const bf16* Sp = S + (size_t)l*Hn + kq*128;
        for (int k8v = 0; k8v < 128; k8v += 8){
          bf16x8 hv = *(const bf16x8*)(hp + k8v);
          bf16x8 sv = *(const bf16x8*)(Sp + k8v);
          #pragma unroll
          for (int j = 0; j < 8; ++j) s += (float)hv[j]*(float)sv[j];
        }
      }
      s += __shfl_xor(s, 1); s += __shfl_xor(s, 2);
      if (kq == 0) sc[l] = (l < slens[row]) ? s : NEGV;
      __syncthreads();
      float mx = -1e30f;
      for (int j = 0; j < Ln; ++j) mx = fmaxf(mx, sc[j]);
      if (tid < Ln) at[tid] = __expf(sc[tid] - mx);
      __syncthreads();
      float den = 0.f;
      for (int j = 0; j < Ln; ++j) den += at[j];
      float inv = 1.f/den;
      int kk = half*256 + tid;
      float cacc = 0.f;
      for (int j = 0; j < Ln; ++j) cacc += at[j]*(float)S[(size_t)j*Hn + kk];
      ctx[(size_t)row*Hn + kk] = (bf16)(cacc*inv);
    }
    gbar(flags, rg*32, 32, cb, sbase+1);
    // ---------- hid: av = [h|ctx] @ Whid^T + hb, K=1024 quarter per wave ----------
    {
      f32x4 acc = {};
      const bf16* ap; const bf16* bp;
      if (w < 2){
        ap = hdb + (rb^1)*HB + (size_t)rowA*Hn + w*256 + hi*8;
        bp = Whid + (size_t)col*1024 + w*256 + hi*8;
      } else {
        ap = ctx + (size_t)rowA*Hn + (w-2)*256 + hi*8;
        bp = Whid + (size_t)col*1024 + 512 + (w-2)*256 + hi*8;
      }
      for (int kb = 0; kb < 8; ++kb){
        bf16x8 av = *(const bf16x8*)(ap + kb*32);
        bf16x8 bv = *(const bf16x8*)(bp + kb*32);
        acc = MFMA16(av, bv, acc);
      }
      #pragma unroll
      for (int r = 0; r < 4; ++r) red[w][lane][r] = acc[r];
      __syncthreads();
      int grow = rg*16 + hi*4 + w;
      float av4 = red[0][lane][w] + red[1][lane][w] + red[2][lane][w] + red[3][lane][w]
                + hbias[col];
      avall[((size_t)t*Bn + grow)*Hn + col] = (bf16)av4;
    }
    gbar(flags, rg*32, 32, cb, sbase+2);
  }
}

// ---------------- target logit ----------------
__global__ void k_tgt(const bf16* __restrict__ av_all, const bf16* __restrict__ Wout,
                      const float* __restrict__ ob, const int* __restrict__ trg_tokens,
                      float* __restrict__ tlog)
{
  int row = blockIdx.x*4 + (threadIdx.x >> 6);
  int lane = threadIdx.x & 63;
  int t = row >> 7, b = row & 127;
  int tok = trg_tokens[b*Tn + t + 1];
  bf16x8 va = *(const bf16x8*)(av_all + (size_t)row*Hn + lane*8);
  bf16x8 vw = *(const bf16x8*)(Wout + (size_t)tok*Hn + lane*8);
  float s = 0.f;
  #pragma unroll
  for (int j = 0; j < 8; ++j) s += (float)va[j]*(float)vw[j];
  #pragma unroll
  for (int sh = 1; sh < 64; sh <<= 1) s += __shfl_xor(s, sh);
  if (lane == 0) tlog[row] = s + ob[tok];
}

// ---------------- final reduce ----------------
__global__ void k_lse(const float* __restrict__ pmax, const float* __restrict__ psum,
                      const float* __restrict__ tlog, const int* __restrict__ tlens,
                      float* __restrict__ out)
{
  int row = blockIdx.x*512 + threadIdx.x;
  float contrib = 0.f;
  if (row < MD){
    float mx = -1e30f;
    for (int pc = 0; pc < 250; ++pc) mx = fmaxf(mx, pmax[(size_t)pc*MD + row]);
    float s = 0.f;
    for (int pc = 0; pc < 250; ++pc)
      s += psum[(size_t)pc*MD + row] * __expf(pmax[(size_t)pc*MD + row] - mx);
    float lse = mx + __logf(s);
    int t = row >> 7, b = row & 127;
    if (t + 1 < tlens[b]) contrib = tlog[row] - lse;
  }
  #pragma unroll
  for (int sh = 1; sh < 64; sh <<= 1) contrib += __shfl_xor(contrib, sh);
  __shared__ float wsum[8];
  if ((threadIdx.x & 63) == 0) wsum[threadIdx.x >> 6] = contrib;
  __syncthreads();
  if (threadIdx.x == 0){
    float s2 = 0.f;
    for (int i = 0; i < 8; ++i) s2 += wsum[i];
    atomicAdd(out, s2);
  }
}

} // namespace

extern "C" void kernel_launch(void* const* d_in, const int* in_sizes, int n_in,
                              void* d_out, int out_size, void* d_ws, size_t ws_size,
                              hipStream_t stream)
{
  (void)in_sizes; (void)n_in; (void)out_size; (void)ws_size;
  const int*   src_tokens = (const int*)  d_in[0];
  const int*   src_lens   = (const int*)  d_in[1];
  const int*   trg_tokens = (const int*)  d_in[2];
  const int*   trg_lens   = (const int*)  d_in[3];
  const float* src_emb    = (const float*)d_in[4];
  const float* trg_emb    = (const float*)d_in[5];
  const float* eWih0 = (const float*)d_in[6];
  const float* eWhh0 = (const float*)d_in[7];
  const float* eb0   = (const float*)d_in[8];
  const float* eWih1 = (const float*)d_in[9];
  const float* eWhh1 = (const float*)d_in[10];
  const float* eb1   = (const float*)d_in[11];
  const float* dWih  = (const float*)d_in[12];
  const float* dWhh  = (const float*)d_in[13];
  const float* db    = (const float*)d_in[14];
  const float* hW    = (const float*)d_in[15];
  const float* hb    = (const float*)d_in[16];
  const float* oW    = (const float*)d_in[17];
  const float* ob    = (const float*)d_in[18];
  const float* iW    = (const float*)d_in[19];
  const float* ib    = (const float*)d_in[20];

  char* p = (char*)d_ws;
  auto alloc = [&](size_t bytes)->void*{
    void* r = (void*)p; p += (bytes + 255) & ~(size_t)255; return r;
  };
  bf16* wih0  = (bf16*)alloc((size_t)G4*En*2);
  bf16* whh0  = (bf16*)alloc((size_t)G4*Hn*2);
  bf16* wih1  = (bf16*)alloc((size_t)G4*Hn*2);
  bf16* whh1  = (bf16*)alloc((size_t)G4*Hn*2);
  bf16* wdih  = (bf16*)alloc((size_t)G4*1024*2);
  bf16* wdhh  = (bf16*)alloc((size_t)G4*Hn*2);
  bf16* whid  = (bf16*)alloc((size_t)Hn*1024*2);
  bf16* wout  = (bf16*)alloc((size_t)Vn*Hn*2);
  bf16* Xe    = (bf16*)alloc((size_t)Ln*Bn*En*2);
  bf16* Vg    = (bf16*)alloc((size_t)TD*Bn*En*2);
  bf16* Sst   = (bf16*)alloc((size_t)Bn*Ln*Hn*2);
  bf16* h1b   = (bf16*)alloc((size_t)2*HB*2);
  bf16* h2b   = (bf16*)alloc((size_t)2*HB*2);
  bf16* hdb   = (bf16*)alloc((size_t)2*HB*2);
  bf16* ctx   = (bf16*)alloc((size_t)HB*2);
  bf16* avall = (bf16*)alloc((size_t)TD*HB*2);
  bf16* Xg    = (bf16*)alloc((size_t)Ln*Bn*G4*2);   // also reused for Gx (24.6MB < 33.5MB)
  float* c1   = (float*)alloc((size_t)HB*4);
  float* c2   = (float*)alloc((size_t)HB*4);
  float* cd   = (float*)alloc((size_t)HB*4);
  float* pmax = (float*)alloc((size_t)250*MD*4);
  float* psum = (float*)alloc((size_t)250*MD*4);
  float* tlog = (float*)alloc((size_t)MD*4);
  int*   eflg = (int*)alloc(256*4);
  int*   dflg = (int*)alloc(256*4);
  float* outp = (float*)d_out;

  auto conv = [&](const float* s, bf16* d, int n){
    int n4 = n/4;
    k_conv<<<(n4+255)/256, 256, 0, stream>>>((const float4*)s, (ushort4*)d, n4);
  };
  conv(eWih0, wih0, G4*En);
  conv(eWhh0, whh0, G4*Hn);
  conv(eWih1, wih1, G4*Hn);
  conv(eWhh1, whh1, G4*Hn);
  conv(dWih,  wdih, G4*1024);
  conv(dWhh,  wdhh, G4*Hn);
  conv(hW,    whid, Hn*1024);
  conv(oW,    wout, Vn*Hn);

  k_gather_src<<<4096, 256, 0, stream>>>(src_tokens, src_emb, (ushort4*)Xe);
  k_gather_trg<<<3008, 256, 0, stream>>>(trg_tokens, trg_emb, (ushort4*)Vg);
  k_zero<<<256, 256, 0, stream>>>(h1b, h2b + HB, c1, c2, eflg, dflg, outp);

  // Xg = Xe @ Wih0^T + b0   (M=8192, N=2048, K=512), bf16 out
  k_gemm2<0><<<dim3(64, 16), 256, 0, stream>>>(Xe, En, wih0, En, eb0,
                                               Xg, G4, nullptr, nullptr, 0);

  // persistent encoder (65 steps, group barriers)
  k_encp<<<256, 256, 0, stream>>>(Xg, h1b, h2b, c1, c2, whh0, wih1, whh1, eb1,
                                  src_lens, Sst, eflg);

  // Gx = Vg @ Wdih_v^T + db  (M=6016, N=2048, K=512) into Xg buffer
  k_gemm2<0><<<dim3(47, 16), 256, 0, stream>>>(Vg, En, wdih, 1024, db,
                                               Xg, G4, nullptr, nullptr, 0);

  // persistent decoder (init + 47 x {gates, attn, hid})
  k_decp<<<256, 256, 0, stream>>>(Xg, avall, avall, hdb, cd, ctx, Sst,
                                  wdih, wdhh, whid, hb, iW, ib, c1, c2,
                                  src_lens, dflg);

  k_tgt<<<1504, 256, 0, stream>>>(avall, wout, ob, trg_tokens, tlog);

  // fused logits + per-128-col logsumexp partials (M=6016, N=32000, K=512)
  k_gemm2<1><<<dim3(47, 250), 256, 0, stream>>>(avall, En, wout, En, ob,
                                                nullptr, 0, pmax, psum, MD);

  k_lse<<<12, 512, 0, stream>>>(pmax, psum, tlog, trg_lens, outp);
}